// Round 3
// baseline (336.179 us; speedup 1.0000x reference)
//
#include <hip/hip_runtime.h>
#include <hip/hip_bf16.h>

#define D 1024

typedef unsigned int u32;
typedef __attribute__((ext_vector_type(4))) unsigned int u32x4;

__device__ __forceinline__ float bflo(u32 u) { return __uint_as_float(u << 16); }
__device__ __forceinline__ float bfhi(u32 u) { return __uint_as_float(u & 0xffff0000u); }
__device__ __forceinline__ float bf1(const void* p, int j) {
    unsigned short s = ((const unsigned short*)p)[j];
    return __uint_as_float(((u32)s) << 16);
}

__device__ __forceinline__ float waveReduceSum(float v) {
#pragma unroll
    for (int off = 32; off > 0; off >>= 1) v += __shfl_xor(v, off, 64);
    return v;
}

// Probe input dtype (1=bf16, 0=fp32): low 16 bits of h_t words as bf16 need
// sane exponents; fp32 low halves are random mantissa bits (~10% pass rate).
__global__ __launch_bounds__(64) void k_probe(const u32* __restrict__ htw,
                                              int* __restrict__ flag) {
    int lane = threadIdx.x;
    u32 w = htw[lane];
    u32 e = (w >> 7) & 0xFF;
    float c = (e >= 100 && e <= 126) ? 1.f : 0.f;
    c = waveReduceSum(c);
    if (lane == 0) *flag = (c >= 56.f) ? 1 : 0;
}

// q[j] = dot(W0[j,:], h_t) + b0[j]
__global__ __launch_bounds__(256) void k_q(const int* __restrict__ flag,
                                           const void* __restrict__ W0,
                                           const void* __restrict__ ht,
                                           const void* __restrict__ b0,
                                           float* __restrict__ q) {
    int wid = threadIdx.x >> 6, lane = threadIdx.x & 63;
    int j = blockIdx.x * 4 + wid;
    int isBf16 = *flag;
    float s = 0.f;
    if (isBf16) {
        const u32x4* wrow = (const u32x4*)((const __hip_bfloat16*)W0 + (size_t)j * D);
        const u32x4* hv = (const u32x4*)ht;
#pragma unroll
        for (int half = 0; half < 2; ++half) {
            u32x4 a = wrow[half * 64 + lane];
            u32x4 b = hv[half * 64 + lane];
#pragma unroll
            for (int t = 0; t < 4; ++t) {
                s += bflo(a[t]) * bflo(b[t]);
                s += bfhi(a[t]) * bfhi(b[t]);
            }
        }
    } else {
        const float4* wrow = (const float4*)((const float*)W0 + (size_t)j * D);
        const float4* hv = (const float4*)ht;
#pragma unroll
        for (int t = 0; t < 4; ++t) {
            float4 a = wrow[t * 64 + lane];
            float4 b = hv[t * 64 + lane];
            s += a.x * b.x + a.y * b.y + a.z * b.z + a.w * b.w;
        }
    }
    s = waveReduceSum(s);
    if (lane == 0) {
        float bias = isBf16 ? bf1(b0, j) : ((const float*)b0)[j];
        q[j] = s + bias;
    }
}

__device__ __forceinline__ void loadRow(const void* __restrict__ Hm, int r,
                                        int isBf16, int lane, float* h) {
    if (isBf16) {
        const u32x4* hr = (const u32x4*)((const __hip_bfloat16*)Hm + (size_t)r * D);
        u32x4 a = hr[lane];
        u32x4 b = hr[64 + lane];
#pragma unroll
        for (int t = 0; t < 4; ++t) {
            h[2 * t] = bflo(a[t]);     h[2 * t + 1] = bfhi(a[t]);
            h[8 + 2 * t] = bflo(b[t]); h[8 + 2 * t + 1] = bfhi(b[t]);
        }
    } else {
        const float4* hr = (const float4*)((const float*)Hm + (size_t)r * D);
#pragma unroll
        for (int t = 0; t < 4; ++t) {
            float4 a = hr[t * 64 + lane];
            h[t * 4 + 0] = a.x; h[t * 4 + 1] = a.y;
            h[t * 4 + 2] = a.z; h[t * 4 + 3] = a.w;
        }
    }
}

__device__ __forceinline__ float dotTree(const float* h, const float* qr) {
    float p[16];
#pragma unroll
    for (int j = 0; j < 16; ++j) p[j] = h[j] * qr[j];
#pragma unroll
    for (int step = 1; step < 16; step <<= 1)
#pragma unroll
        for (int j = 0; j < 16; j += 2 * step) p[j] += p[j + step];
    return p[0];
}

// Fused pass over H: w_i = exp(exp(H_i.q)); accumulate sum(w_i), sum(w_i*H_i).
// Per-block partials written contention-free; reduced by k_fin.
__global__ __launch_bounds__(512) void k_pass(const int* __restrict__ flag,
                                              const void* __restrict__ Hm,
                                              const float* __restrict__ q,
                                              float* __restrict__ accp,  // [B][D]
                                              float* __restrict__ lvals, // [B]
                                              int N, int totalWaves) {
    __shared__ float lacc[8][D];
    __shared__ float ll[8];
    int wid = threadIdx.x >> 6, lane = threadIdx.x & 63;
    int gw = blockIdx.x * 8 + wid;
    int isBf16 = *flag;

    int col[16];
    if (isBf16) {
#pragma unroll
        for (int j = 0; j < 8; ++j) { col[j] = lane * 8 + j; col[8 + j] = 512 + lane * 8 + j; }
    } else {
#pragma unroll
        for (int t = 0; t < 4; ++t)
#pragma unroll
            for (int u = 0; u < 4; ++u) col[t * 4 + u] = t * 256 + lane * 4 + u;
    }
    float qr[16];
#pragma unroll
    for (int j = 0; j < 16; ++j) qr[j] = q[col[j]];

    float l = 0.f;
    float acc[16];
#pragma unroll
    for (int j = 0; j < 16; ++j) acc[j] = 0.f;

    int r = gw;
    // two rows per iteration: the two shuffle-reduce chains overlap
    for (; r + totalWaves < N; r += 2 * totalWaves) {
        float h0[16], h1[16];
        loadRow(Hm, r, isBf16, lane, h0);
        loadRow(Hm, r + totalWaves, isBf16, lane, h1);
        float d0 = dotTree(h0, qr);
        float d1 = dotTree(h1, qr);
        d0 = waveReduceSum(d0);
        d1 = waveReduceSum(d1);
        float p0 = __expf(__expf(d0));
        float p1 = __expf(__expf(d1));
        l += p0 + p1;
#pragma unroll
        for (int j = 0; j < 16; ++j) acc[j] += p0 * h0[j] + p1 * h1[j];
    }
    if (r < N) {
        float h0[16];
        loadRow(Hm, r, isBf16, lane, h0);
        float d0 = waveReduceSum(dotTree(h0, qr));
        float p0 = __expf(__expf(d0));
        l += p0;
#pragma unroll
        for (int j = 0; j < 16; ++j) acc[j] += p0 * h0[j];
    }

#pragma unroll
    for (int j = 0; j < 16; ++j) lacc[wid][col[j]] = acc[j];
    if (lane == 0) ll[wid] = l;
    __syncthreads();
    float* dst = accp + (size_t)blockIdx.x * D;
    for (int k = threadIdx.x; k < D; k += 512) {
        float s = 0.f;
#pragma unroll
        for (int w = 0; w < 8; ++w) s += lacc[w][k];
        dst[k] = s;
    }
    if (threadIdx.x == 0) {
        float s = 0.f;
#pragma unroll
        for (int w = 0; w < 8; ++w) s += ll[w];
        lvals[blockIdx.x] = s;
    }
}

// e_s[k] = sum_b accp[b][k]; Ls = sum_b lvals[b]. grid = D/64 blocks.
__global__ __launch_bounds__(256) void k_fin(const float* __restrict__ accp,
                                             const float* __restrict__ lvals,
                                             float* __restrict__ e_s,
                                             float* __restrict__ Ls, int B) {
    __shared__ float part[4][64];
    int t = threadIdx.x, lane = t & 63, chunk = t >> 6;
    int col = blockIdx.x * 64 + lane;
    int rpc = B >> 2;
    float s = 0.f;
    for (int b = chunk * rpc; b < (chunk + 1) * rpc; ++b)
        s += accp[(size_t)b * D + col];
    part[chunk][lane] = s;
    __syncthreads();
    if (t < 64) e_s[col] = part[0][lane] + part[1][lane] + part[2][lane] + part[3][lane];
    if (blockIdx.x == 0 && chunk == 3) {
        float ls = 0.f;
        for (int b = lane; b < B; b += 64) ls += lvals[b];
        ls = waveReduceSum(ls);
        if (lane == 0) *Ls = ls;
    }
}

// out[j] = tanh(dot(W1[j,:], e_s)/Ls + b1[j] + dot(W2[j,:], h_t) + b2[j])
__global__ __launch_bounds__(256) void k_out(const int* __restrict__ flag,
                                             const void* __restrict__ W1,
                                             const void* __restrict__ b1,
                                             const void* __restrict__ W2,
                                             const void* __restrict__ b2,
                                             const void* __restrict__ ht,
                                             const float* __restrict__ e_s,
                                             const float* __restrict__ Ls,
                                             void* __restrict__ out) {
    int wid = threadIdx.x >> 6, lane = threadIdx.x & 63;
    int j = blockIdx.x * 4 + wid;
    int isBf16 = *flag;
    float s1 = 0.f, s2 = 0.f;
    if (isBf16) {
        const u32x4* w1r = (const u32x4*)((const __hip_bfloat16*)W1 + (size_t)j * D);
        const u32x4* w2r = (const u32x4*)((const __hip_bfloat16*)W2 + (size_t)j * D);
        const u32x4* hv = (const u32x4*)ht;
        int c0 = lane * 8;
#pragma unroll
        for (int half = 0; half < 2; ++half) {
            u32x4 a = w1r[half * 64 + lane];
            u32x4 b = w2r[half * 64 + lane];
            u32x4 hh = hv[half * 64 + lane];
            const float4* ev = (const float4*)(e_s + half * 512 + c0);
            float4 ea = ev[0], eb = ev[1];
            float e[8] = {ea.x, ea.y, ea.z, ea.w, eb.x, eb.y, eb.z, eb.w};
#pragma unroll
            for (int t = 0; t < 4; ++t) {
                s1 += bflo(a[t]) * e[2 * t] + bfhi(a[t]) * e[2 * t + 1];
                s2 += bflo(b[t]) * bflo(hh[t]) + bfhi(b[t]) * bfhi(hh[t]);
            }
        }
    } else {
        const float4* w1r = (const float4*)((const float*)W1 + (size_t)j * D);
        const float4* w2r = (const float4*)((const float*)W2 + (size_t)j * D);
        const float4* hv = (const float4*)ht;
        const float4* ev = (const float4*)e_s;
#pragma unroll
        for (int t = 0; t < 4; ++t) {
            float4 a = w1r[t * 64 + lane];
            float4 b = w2r[t * 64 + lane];
            float4 hh = hv[t * 64 + lane];
            float4 ee = ev[t * 64 + lane];
            s1 += a.x * ee.x + a.y * ee.y + a.z * ee.z + a.w * ee.w;
            s2 += b.x * hh.x + b.y * hh.y + b.z * hh.z + b.w * hh.w;
        }
    }
    s1 = waveReduceSum(s1);
    s2 = waveReduceSum(s2);
    if (lane == 0) {
        float bias1 = isBf16 ? bf1(b1, j) : ((const float*)b1)[j];
        float bias2 = isBf16 ? bf1(b2, j) : ((const float*)b2)[j];
        float r = tanhf(s1 / (*Ls) + bias1 + s2 + bias2);
        if (isBf16) ((__hip_bfloat16*)out)[j] = __float2bfloat16(r);
        else        ((float*)out)[j] = r;
    }
}

extern "C" void kernel_launch(void* const* d_in, const int* in_sizes, int n_in,
                              void* d_out, int out_size, void* d_ws, size_t ws_size,
                              hipStream_t stream) {
    const void* H  = d_in[0];
    const void* ht = d_in[1];
    const void* W0 = d_in[2];
    const void* b0 = d_in[3];
    const void* W1 = d_in[4];
    const void* b1 = d_in[5];
    const void* W2 = d_in[6];
    const void* b2 = d_in[7];
    int N = in_sizes[0] / D;

    float* wsf  = (float*)d_ws;
    int*   flag = (int*)wsf;          // [1]
    float* Ls   = wsf + 1;            // [1]
    float* q    = wsf + 64;           // [1024]
    float* e_s  = wsf + 1088;         // [1024] (16B aligned)
    float* lvals= wsf + 2112;         // [B]
    float* accp = wsf + 4096;         // [B][1024]

    int B = 512;  // k_pass blocks, 8 waves each
    while (B > 64 && ws_size < (size_t)(4096 + (size_t)B * D) * 4) B >>= 1;

    k_probe<<<1, 64, 0, stream>>>((const u32*)ht, flag);
    k_q<<<256, 256, 0, stream>>>(flag, W0, ht, b0, q);
    k_pass<<<B, 512, 0, stream>>>(flag, H, q, accp, lvals, N, B * 8);
    k_fin<<<D / 64, 256, 0, stream>>>(accp, lvals, e_s, Ls, B);
    k_out<<<256, 256, 0, stream>>>(flag, W1, b1, W2, b2, ht, e_s, Ls, d_out);
}